// Round 18
// baseline (1128.247 us; speedup 1.0000x reference)
//
#include <hip/hip_runtime.h>
#include <hip/hip_bf16.h>

typedef __bf16 bf16x8 __attribute__((ext_vector_type(8)));
typedef __bf16 bf16x4 __attribute__((ext_vector_type(4)));
typedef float  f32x4  __attribute__((ext_vector_type(4)));

#define MFMA_BF16(A_, B_, C_) __builtin_amdgcn_mfma_f32_16x16x32_bf16(A_, B_, C_, 0, 0, 0)

static constexpr int    HIDC  = 768;
static constexpr int    BB    = 64;
static constexpr int    LL    = 1024;
static constexpr int    MROWS = BB * LL;          // 65536
static constexpr int    NHEAD = 12;
static constexpr int    HD    = 64;
static constexpr size_t QKV1  = (size_t)BB * NHEAD * LL * HD;   // 50331648 elems
static constexpr float  QSCALE = 0.1803368801111204f;           // 0.125 * log2(e)

// ---- workspace layout (bytes) ----
static constexpr size_t OFF_WQKVT = 0;                                    // bf16 [2304][768] (+wo,w1,w2 after)
static constexpr size_t OFF_WOT   = OFF_WQKVT + (size_t)2304 * 768 * 2;
static constexpr size_t OFF_W1T   = OFF_WOT   + (size_t)768 * 768 * 2;
static constexpr size_t OFF_W2T   = OFF_W1T   + (size_t)768 * 768 * 2;
static constexpr size_t OFF_BQKV  = OFF_W2T   + (size_t)768 * 768 * 2;    // f32 [2304]
static constexpr size_t OFF_C     = OFF_BQKV  + (size_t)2304 * 4;         // f32 [64][4608]
static constexpr size_t OFF_H     = OFF_C     + (size_t)64 * 4608 * 4;    // bf16 h / h2
static constexpr size_t OFF_AO    = OFF_H     + (size_t)MROWS * HIDC * 2; // bf16 attn_out / mlp_h
static constexpr size_t OFF_QKV   = OFF_AO    + (size_t)MROWS * HIDC * 2; // bf16 q,k,[v frag]; later bf16 x

__device__ __forceinline__ void async16(const __bf16* g, __bf16* l) {
    __builtin_amdgcn_global_load_lds((const __attribute__((address_space(1))) void*)g,
                                     (__attribute__((address_space(3))) void*)l, 16, 0, 0);
}

#define PH_BARRIER() do { __builtin_amdgcn_sched_barrier(0); asm volatile("" ::: "memory"); \
    __builtin_amdgcn_s_barrier(); asm volatile("" ::: "memory"); __builtin_amdgcn_sched_barrier(0); } while (0)

// ---------------- weight transpose + cast (LDS-tiled, coalesced): dst[n][k] = bf16(src[k][n]) ----------------
__global__ __launch_bounds__(256) void tcvt6_k(const float* __restrict__ s0, const float* __restrict__ s1,
                                               const float* __restrict__ s2, const float* __restrict__ s3,
                                               const float* __restrict__ s4, const float* __restrict__ s5,
                                               __bf16* __restrict__ dbase) {
    __shared__ float t[64][65];
    const int bid = blockIdx.x;           // 6 * 144
    const int widx = bid / 144;
    const int tb = bid - widx * 144;      // 12x12 tiles of 64
    const int kt = tb / 12, nt = tb - kt * 12;
    const float* src = (widx == 0) ? s0 : (widx == 1) ? s1 : (widx == 2) ? s2
                     : (widx == 3) ? s3 : (widx == 4) ? s4 : s5;
    const int tid = threadIdx.x;
    const int r = tid >> 4, c4 = (tid & 15) * 4;
    #pragma unroll
    for (int i = 0; i < 4; ++i) {
        const float4 v = *(const float4*)(src + (size_t)(kt * 64 + r + 16 * i) * 768 + nt * 64 + c4);
        t[r + 16 * i][c4 + 0] = v.x; t[r + 16 * i][c4 + 1] = v.y;
        t[r + 16 * i][c4 + 2] = v.z; t[r + 16 * i][c4 + 3] = v.w;
    }
    __syncthreads();
    const int n = tid >> 2, kg = (tid & 3) * 8;
    #pragma unroll
    for (int i = 0; i < 2; ++i) {
        const int k = kg + i * 32;
        bf16x8 o;
        #pragma unroll
        for (int j = 0; j < 8; ++j) o[j] = (__bf16)t[k + j][n];
        *(bf16x8*)(dbase + (size_t)widx * 768 * 768 + (size_t)(nt * 64 + n) * 768 + kt * 64 + k) = o;
    }
}

__global__ __launch_bounds__(256) void bcat_k(const float* __restrict__ bq, const float* __restrict__ bk,
                                              const float* __restrict__ bv, float* __restrict__ bqkv) {
    int i = blockIdx.x * 256 + threadIdx.x;
    if (i < 2304) {
        int w = i / 768, r = i - w * 768;
        const float* p = (w == 0) ? bq : (w == 1) ? bk : bv;
        bqkv[i] = p[r];
    }
}

// ---------------- adaLN: c[64][4608] = silu(cond) @ w_ada + b_ada ----------------
__global__ __launch_bounds__(256) void ada_k(const float* __restrict__ cond, const float* __restrict__ w_ada,
                                             const float* __restrict__ b_ada, float* __restrict__ c) {
    __shared__ float s[8][768];
    const int tid = threadIdx.x;
    const int bt = blockIdx.x / 18;
    const int nt = blockIdx.x % 18;
    #pragma unroll
    for (int i = 0; i < 24; ++i) {
        int idx = i * 256 + tid;
        int bb = idx / 768, kk = idx - bb * 768;
        float v = cond[(size_t)(bt * 8 + bb) * 768 + kk];
        s[bb][kk] = v / (1.f + __expf(-v));
    }
    __syncthreads();
    const int n = nt * 256 + tid;
    float acc[8];
    #pragma unroll
    for (int j = 0; j < 8; ++j) acc[j] = 0.f;
    for (int k = 0; k < 768; ++k) {
        float w = w_ada[(size_t)k * 4608 + n];
        #pragma unroll
        for (int j = 0; j < 8; ++j) acc[j] += s[j][k] * w;
    }
    float bias = b_ada[n];
    #pragma unroll
    for (int j = 0; j < 8; ++j) c[(size_t)(bt * 8 + j) * 4608 + n] = acc[j] + bias;
}

// ---------------- LayerNorm + modulate, wave-per-row (f32 input) -> bf16 ----------------
__global__ __launch_bounds__(256) void ln_mod_f4_k(const float* __restrict__ x,
                                                   const float* __restrict__ lns, const float* __restrict__ lnb,
                                                   const float* __restrict__ c, int shift_off, int scale_off,
                                                   __bf16* __restrict__ out) {
    const int wave = threadIdx.x >> 6, lane = threadIdx.x & 63;
    const int row = blockIdx.x * 4 + wave;
    const size_t base = (size_t)row * HIDC;
    const int b = row >> 10;
    float4 v[3];
    #pragma unroll
    for (int i = 0; i < 3; ++i) v[i] = *(const float4*)(x + base + (i * 64 + lane) * 4);
    float s = 0.f, ss = 0.f;
    #pragma unroll
    for (int i = 0; i < 3; ++i) {
        s  += v[i].x + v[i].y + v[i].z + v[i].w;
        ss += v[i].x * v[i].x + v[i].y * v[i].y + v[i].z * v[i].z + v[i].w * v[i].w;
    }
    #pragma unroll
    for (int off = 1; off < 64; off <<= 1) { s += __shfl_xor(s, off); ss += __shfl_xor(ss, off); }
    const float mu   = s * (1.f / 768.f);
    const float var  = ss * (1.f / 768.f) - mu * mu;
    const float rstd = rsqrtf(var + 1e-6f);
    const float* cb = c + (size_t)b * 4608;
    #pragma unroll
    for (int i = 0; i < 3; ++i) {
        bf16x4 o;
        const float vv[4] = {v[i].x, v[i].y, v[i].z, v[i].w};
        #pragma unroll
        for (int j = 0; j < 4; ++j) {
            const int col = (i * 64 + lane) * 4 + j;
            float val = (vv[j] - mu) * rstd * lns[col] + lnb[col];
            val = val * (1.f + cb[scale_off + col]) + cb[shift_off + col];
            o[j] = (__bf16)val;
        }
        *(bf16x4*)(out + base + (i * 64 + lane) * 4) = o;
    }
}

// ---------------- LayerNorm + modulate, wave-per-row (bf16 input) -> bf16 ----------------
__global__ __launch_bounds__(256) void ln_mod_b_k(const __bf16* __restrict__ x,
                                                  const float* __restrict__ lns, const float* __restrict__ lnb,
                                                  const float* __restrict__ c, int shift_off, int scale_off,
                                                  __bf16* __restrict__ out) {
    const int wave = threadIdx.x >> 6, lane = threadIdx.x & 63;
    const int row = blockIdx.x * 4 + wave;
    const size_t base = (size_t)row * HIDC;
    const int b = row >> 10;
    float v[12];
    #pragma unroll
    for (int i = 0; i < 3; ++i) {
        const bf16x4 xv = *(const bf16x4*)(x + base + (i * 64 + lane) * 4);
        #pragma unroll
        for (int j = 0; j < 4; ++j) v[i * 4 + j] = (float)xv[j];
    }
    float s = 0.f, ss = 0.f;
    #pragma unroll
    for (int i = 0; i < 12; ++i) { s += v[i]; ss += v[i] * v[i]; }
    #pragma unroll
    for (int off = 1; off < 64; off <<= 1) { s += __shfl_xor(s, off); ss += __shfl_xor(ss, off); }
    const float mu   = s * (1.f / 768.f);
    const float var  = ss * (1.f / 768.f) - mu * mu;
    const float rstd = rsqrtf(var + 1e-6f);
    const float* cb = c + (size_t)b * 4608;
    #pragma unroll
    for (int i = 0; i < 3; ++i) {
        bf16x4 o;
        #pragma unroll
        for (int j = 0; j < 4; ++j) {
            const int col = (i * 64 + lane) * 4 + j;
            float val = (v[i * 4 + j] - mu) * rstd * lns[col] + lnb[col];
            val = val * (1.f + cb[scale_off + col]) + cb[shift_off + col];
            o[j] = (__bf16)val;
        }
        *(bf16x4*)(out + base + (i * 64 + lane) * 4) = o;
    }
}

// ================ 256x256 GEMM: 2 barriers/K-tile (round-16, QKV only) ================
template<int EPI>
__global__ __launch_bounds__(512, 2) void gemm256_k(const __bf16* __restrict__ A, const __bf16* __restrict__ BT,
                                                    const float* __restrict__ bias, int NBLK,
                                                    void* __restrict__ out0) {
    constexpr int K = 768;
    constexpr int NKT = K / 64;           // 12 K-tiles
    __shared__ __attribute__((aligned(16))) unsigned char LDSB[131072];
    const int tid = threadIdx.x;
    const int nwg = gridDim.x;
    const int cpx = nwg >> 3;
    const int bid = blockIdx.x;
    const int swz = (bid & 7) * cpx + (bid >> 3);   // XCD-aware, bijective (nwg%8==0)
    const int mb = swz / NBLK, nb = swz - mb * NBLK;
    const size_t m0 = (size_t)mb * 256;
    const int n0 = nb * 256;
    const int wave = tid >> 6, lane = tid & 63;
    const int wm = wave >> 2, wn = wave & 3;
    const int lr = lane & 15, lg = lane >> 4;

    int prow[2], pcol[2], pphys[2];
    #pragma unroll
    for (int i = 0; i < 2; ++i) {
        int p = (i * 512 + tid) * 16;
        prow[i]  = p >> 7;
        pcol[i]  = ((p & 127) ^ ((prow[i] & 7) << 4)) >> 1;
        pphys[i] = p;
    }
    auto STAGE = [&](const __bf16* gbase, size_t rowstart, int kt, int regoff) {
        #pragma unroll
        for (int i = 0; i < 2; ++i) {
            const __bf16* g = gbase + (rowstart + (size_t)prow[i]) * K + kt * 64 + pcol[i];
            async16(g, (__bf16*)(LDSB + regoff + pphys[i]));
        }
    };
    auto AFRAG = [&](int db, int mf, int ks) -> bf16x8 {
        const int row = mf * 16 + lr;
        const int ph = row * 128 + ((ks * 64 + lg * 16) ^ ((row & 7) << 4));
        return *(const bf16x8*)(LDSB + db * 65536 + wm * 16384 + ph);
    };
    auto BFRAG = [&](int db, int nf, int ks) -> bf16x8 {
        const int row = (wn & 1) * 64 + nf * 16 + lr;
        const int ph = row * 128 + ((ks * 64 + lg * 16) ^ ((row & 7) << 4));
        return *(const bf16x8*)(LDSB + db * 65536 + 32768 + (wn >> 1) * 16384 + ph);
    };

    f32x4 acc[8][4];
    #pragma unroll
    for (int i = 0; i < 8; ++i)
        #pragma unroll
        for (int j = 0; j < 4; ++j) acc[i][j] = (f32x4){0.f, 0.f, 0.f, 0.f};
    bf16x8 Af[4][2], Af2[4][2], Bf[4][2];

    STAGE(BT, (size_t)n0,       0, 32768);
    STAGE(BT, (size_t)n0 + 128, 0, 49152);
    STAGE(A,  m0,               0, 0);
    STAGE(A,  m0 + 128,         0, 16384);
    STAGE(BT, (size_t)n0,       1, 65536 + 32768);
    STAGE(BT, (size_t)n0 + 128, 1, 65536 + 49152);
    asm volatile("s_waitcnt vmcnt(4)" ::: "memory");
    PH_BARRIER();

    #pragma unroll 2
    for (int g = 0; g < NKT; ++g) {
        const int db = g & 1, dbn = db ^ 1;
        #pragma unroll
        for (int mf = 0; mf < 4; ++mf) { Af[mf][0] = AFRAG(db, mf, 0); Af[mf][1] = AFRAG(db, mf, 1); }
        #pragma unroll
        for (int nf = 0; nf < 4; ++nf) { Bf[nf][0] = BFRAG(db, nf, 0); Bf[nf][1] = BFRAG(db, nf, 1); }
        if (g + 1 < NKT) {
            STAGE(A, m0,       g + 1, dbn * 65536);
            STAGE(A, m0 + 128, g + 1, dbn * 65536 + 16384);
        }
        __builtin_amdgcn_s_setprio(1);
        #pragma unroll
        for (int ks = 0; ks < 2; ++ks)
            #pragma unroll
            for (int mf = 0; mf < 4; ++mf)
                #pragma unroll
                for (int nf = 0; nf < 4; ++nf)
                    acc[mf][nf] = MFMA_BF16(Af[mf][ks], Bf[nf][ks], acc[mf][nf]);
        __builtin_amdgcn_s_setprio(0);
        PH_BARRIER();
        #pragma unroll
        for (int mf = 0; mf < 4; ++mf) { Af2[mf][0] = AFRAG(db, mf + 4, 0); Af2[mf][1] = AFRAG(db, mf + 4, 1); }
        if (g + 2 < NKT) {
            STAGE(BT, (size_t)n0,       g + 2, db * 65536 + 32768);
            STAGE(BT, (size_t)n0 + 128, g + 2, db * 65536 + 49152);
        }
        __builtin_amdgcn_s_setprio(1);
        #pragma unroll
        for (int ks = 0; ks < 2; ++ks)
            #pragma unroll
            for (int mf = 0; mf < 4; ++mf)
                #pragma unroll
                for (int nf = 0; nf < 4; ++nf)
                    acc[mf + 4][nf] = MFMA_BF16(Af2[mf][ks], Bf[nf][ks], acc[mf + 4][nf]);
        __builtin_amdgcn_s_setprio(0);
        if (g < NKT - 2)       asm volatile("s_waitcnt vmcnt(4)" ::: "memory");
        else if (g == NKT - 2) asm volatile("s_waitcnt vmcnt(0)" ::: "memory");
        if (g + 1 < NKT) PH_BARRIER();
    }

    #pragma unroll
    for (int mf = 0; mf < 8; ++mf) {
        #pragma unroll
        for (int nf = 0; nf < 4; ++nf) {
            const int col = wn * 64 + nf * 16 + lr;
            const int n = n0 + col;
            const int row0 = wm * 128 + mf * 16 + lg * 4;
            const size_t mbase = m0 + row0;
            float v4[4];
            #pragma unroll
            for (int r = 0; r < 4; ++r) v4[r] = acc[mf][nf][r] + bias[n];
            // EPI==0 only (QKV scatter)
            const int which = n / 768, rem = n - which * 768;
            const int hh = rem >> 6, dd = rem & 63;
            const size_t bI = mbase >> 10;
            const size_t lI0 = mbase & 1023;
            if (which == 0) {
                #pragma unroll
                for (int r = 0; r < 4; ++r)
                    ((__bf16*)out0)[(((size_t)bI * NHEAD + hh) * LL + lI0 + r) * HD + dd] = (__bf16)(v4[r] * QSCALE);
            } else if (which == 1) {
                #pragma unroll
                for (int r = 0; r < 4; ++r)
                    ((__bf16*)out0)[QKV1 + (((size_t)bI * NHEAD + hh) * LL + lI0 + r) * HD + dd] = (__bf16)v4[r];
            } else {
                const int tile = (int)(lI0 >> 6), kv = (int)(lI0 & 63);
                const int ks = kv >> 5, r5 = kv & 31;
                const int lgj = (r5 >> 2) & 3;
                const int jb = (r5 >> 4) << 2;
                const int of = dd >> 4, lr2 = dd & 15;
                bf16x4 pk;
                #pragma unroll
                for (int r = 0; r < 4; ++r) pk[r] = (__bf16)v4[r];
                *(bf16x4*)((__bf16*)out0 + 2 * QKV1 + ((size_t)bI * NHEAD + hh) * (LL * HD)
                           + (size_t)tile * 4096 + ((ks * 4 + of) * 64 + lgj * 16 + lr2) * 8 + jb) = pk;
            }
        }
    }
}

// ================ 128x128 GEMM (m97 shape): BK=32, 4 waves, 32KB LDS -> 3 blocks/CU ================
// Single barrier/K-step; co-resident blocks cover each other's drains.
// EPI: 2 = silu->bf16; 3 = x_img(f32)+gate*val->bf16; 4 = x(bf16)+gate*val->f32
template<int EPI>
__global__ __launch_bounds__(256, 2) void gemm128_k(const __bf16* __restrict__ A, const __bf16* __restrict__ BT,
                                                    const float* __restrict__ bias, int NBLK,
                                                    const float* __restrict__ e_res, const __bf16* __restrict__ e_resb,
                                                    const float* __restrict__ e_gate, void* __restrict__ out0) {
    constexpr int K = 768;
    constexpr int NKT = K / 32;          // 24 K-tiles
    __shared__ __attribute__((aligned(16))) unsigned char LDSB[32768];
    const int tid = threadIdx.x;
    const int nwg = gridDim.x;           // 3072 (%8==0)
    const int cpx = nwg >> 3;
    const int bid = blockIdx.x;
    const int swz = (bid & 7) * cpx + (bid >> 3);
    const int mb = swz / NBLK, nb = swz - mb * NBLK;
    const size_t m0 = (size_t)mb * 128;
    const int n0 = nb * 128;
    const int wave = tid >> 6, lane = tid & 63;
    const int wm = wave >> 1, wn = wave & 1;
    const int lr = lane & 15, lg = lane >> 4;

    // staging: thread covers 2 chunks of each 8KB region; source pre-swizzled (c ^= ((row>>1)&3)<<4)
    int prow[2], pcol[2], pphys[2];
    #pragma unroll
    for (int i = 0; i < 2; ++i) {
        int p = (i * 256 + tid) * 16;
        prow[i]  = p >> 6;                                    // row 0..127 (64B rows)
        pcol[i]  = ((p & 63) ^ (((prow[i] >> 1) & 3) << 4)) >> 1;
        pphys[i] = p;
    }
    auto STAGE = [&](const __bf16* gbase, size_t rowstart, int kt, int dstoff) {
        #pragma unroll
        for (int i = 0; i < 2; ++i) {
            const __bf16* g = gbase + (rowstart + (size_t)prow[i]) * K + kt * 32 + pcol[i];
            async16(g, (__bf16*)(LDSB + dstoff + pphys[i]));
        }
    };
    auto AFRAG = [&](int db, int mf) -> bf16x8 {
        const int row = wm * 64 + mf * 16 + lr;
        const int ph = row * 64 + ((lg * 16) ^ (((row >> 1) & 3) << 4));
        return *(const bf16x8*)(LDSB + db * 16384 + ph);
    };
    auto BFRAG = [&](int db, int nf) -> bf16x8 {
        const int row = wn * 64 + nf * 16 + lr;
        const int ph = row * 64 + ((lg * 16) ^ (((row >> 1) & 3) << 4));
        return *(const bf16x8*)(LDSB + db * 16384 + 8192 + ph);
    };

    f32x4 acc[4][4];
    #pragma unroll
    for (int i = 0; i < 4; ++i)
        #pragma unroll
        for (int j = 0; j < 4; ++j) acc[i][j] = (f32x4){0.f, 0.f, 0.f, 0.f};
    bf16x8 Af[4], Bf[4];

    STAGE(A,  m0,         0, 0);
    STAGE(BT, (size_t)n0, 0, 8192);
    asm volatile("s_waitcnt vmcnt(0)" ::: "memory");
    PH_BARRIER();

    #pragma unroll 2
    for (int g = 0; g < NKT; ++g) {
        const int db = g & 1, dbn = db ^ 1;
        #pragma unroll
        for (int mf = 0; mf < 4; ++mf) Af[mf] = AFRAG(db, mf);
        #pragma unroll
        for (int nf = 0; nf < 4; ++nf) Bf[nf] = BFRAG(db, nf);
        if (g + 1 < NKT) {
            STAGE(A,  m0,         g + 1, dbn * 16384);
            STAGE(BT, (size_t)n0, g + 1, dbn * 16384 + 8192);
        }
        __builtin_amdgcn_s_setprio(1);
        #pragma unroll
        for (int mf = 0; mf < 4; ++mf)
            #pragma unroll
            for (int nf = 0; nf < 4; ++nf)
                acc[mf][nf] = MFMA_BF16(Af[mf], Bf[nf], acc[mf][nf]);
        __builtin_amdgcn_s_setprio(0);
        asm volatile("s_waitcnt vmcnt(0)" ::: "memory");
        if (g + 1 < NKT) PH_BARRIER();
    }

    #pragma unroll
    for (int mf = 0; mf < 4; ++mf) {
        #pragma unroll
        for (int nf = 0; nf < 4; ++nf) {
            const int col = wn * 64 + nf * 16 + lr;
            const int n = n0 + col;
            const int row0 = wm * 64 + mf * 16 + lg * 4;
            const size_t mbase = m0 + row0;
            float v4[4];
            #pragma unroll
            for (int r = 0; r < 4; ++r) v4[r] = acc[mf][nf][r] + bias[n];
            #pragma unroll
            for (int r = 0; r < 4; ++r) {
                const size_t m = mbase + r;
                if constexpr (EPI == 2) {
                    float sv = v4[r] / (1.f + __expf(-v4[r]));
                    ((__bf16*)out0)[m * HIDC + n] = (__bf16)sv;
                } else if constexpr (EPI == 3) {
                    size_t bI = m >> 10;
                    float gg = e_gate[bI * 4608 + n];
                    ((__bf16*)out0)[m * HIDC + n] = (__bf16)(e_res[m * HIDC + n] + gg * v4[r]);
                } else {
                    size_t bI = m >> 10;
                    float gg = e_gate[bI * 4608 + n];
                    ((float*)out0)[m * HIDC + n] = (float)e_resb[m * HIDC + n] + gg * v4[r];
                }
            }
        }
    }
}

// ================ flash attention: 4-wave blocks (measured best), ring-2, unshifted exp2 ================
__global__ __launch_bounds__(256, 4) void attn_k(const __bf16* __restrict__ qb, const __bf16* __restrict__ kb,
                                                 const __bf16* __restrict__ v2g, __bf16* __restrict__ out) {
    __shared__ __attribute__((aligned(16))) unsigned char LDSA[32768];
    const int nwg = gridDim.x;       // 6144
    const int cpx = nwg >> 3;
    const int bid = blockIdx.x;
    const int swz = (bid & 7) * cpx + (bid >> 3);
    const int bh = swz >> 3;
    const int qt = swz & 7;
    const int b = bh / NHEAD, h = bh - b * NHEAD;
    const int tid = threadIdx.x;
    const int wave = tid >> 6, lane = tid & 63;
    const int lr = lane & 15, lg = lane >> 4;
    const size_t base = (size_t)bh * LL * HD;    // q,k: [bh][l][d]; v2: [bh][tile][4096]

    const int q0 = qt * 128 + wave * 32;
    bf16x8 qf[2][2];
    #pragma unroll
    for (int qi = 0; qi < 2; ++qi) {
        const __bf16* qrow = qb + base + (size_t)(q0 + qi * 16 + lr) * HD;
        qf[qi][0] = *(const bf16x8*)(qrow + lg * 8);
        qf[qi][1] = *(const bf16x8*)(qrow + 32 + lg * 8);
    }
    __builtin_amdgcn_sched_barrier(0);

    int krow[2], kcol[2];
    #pragma unroll
    for (int i = 0; i < 2; ++i) {
        int pp = (i * 256 + tid) * 16;
        krow[i] = pp >> 7;
        kcol[i] = (pp & 127) ^ ((krow[i] & 7) << 4);
    }
    auto STAGE = [&](int t) {
        unsigned char* Lb = LDSA + (t & 1) * 16384;
        const int kv0 = t * 64;
        #pragma unroll
        for (int i = 0; i < 2; ++i) {
            const __bf16* g = kb + base + (size_t)(kv0 + krow[i]) * HD + (kcol[i] >> 1);
            async16(g, (__bf16*)(Lb + (i * 256 + tid) * 16));
        }
        #pragma unroll
        for (int i = 0; i < 2; ++i) {
            int pp = (i * 256 + tid) * 16;
            const __bf16* g = v2g + base + (size_t)t * 4096 + (pp >> 1);
            async16(g, (__bf16*)(Lb + 8192 + pp));
        }
    };

    bf16x8 vones;
    #pragma unroll
    for (int j = 0; j < 8; ++j) vones[j] = (__bf16)1.0f;

    f32x4 acc[2][4];
    f32x4 accl[2];    // ones-MFMA row-sum accumulator (reg 0 used)
    #pragma unroll
    for (int qi = 0; qi < 2; ++qi) {
        accl[qi] = (f32x4){0.f, 0.f, 0.f, 0.f};
        #pragma unroll
        for (int i = 0; i < 4; ++i) acc[qi][i] = (f32x4){0.f, 0.f, 0.f, 0.f};
    }

    STAGE(0);

    for (int t = 0; t < LL / 64; ++t) {
        asm volatile("s_waitcnt vmcnt(0)" ::: "memory");
        PH_BARRIER();
        if (t + 1 < LL / 64) STAGE(t + 1);
        const unsigned char* KB = LDSA + (t & 1) * 16384;
        const unsigned char* VB = KB + 8192;

        f32x4 s[2][4];
        #pragma unroll
        for (int sf = 0; sf < 4; ++sf) {
            const int row = sf * 16 + lr;
            const bf16x8 kf0 = *(const bf16x8*)(KB + row * 128 + ((lg * 16) ^ ((row & 7) << 4)));
            const bf16x8 kf1 = *(const bf16x8*)(KB + row * 128 + ((64 + lg * 16) ^ ((row & 7) << 4)));
            #pragma unroll
            for (int qi = 0; qi < 2; ++qi) {
                f32x4 tt = (f32x4){0.f, 0.f, 0.f, 0.f};
                tt = MFMA_BF16(kf0, qf[qi][0], tt);
                tt = MFMA_BF16(kf1, qf[qi][1], tt);
                s[qi][sf] = tt;
            }
        }
        // P = exp2(S) — unshifted; exact normalization by ones-MFMA row-sum at the end
        #pragma unroll
        for (int ks = 0; ks < 2; ++ks) {
            bf16x8 pb[2];
            #pragma unroll
            for (int qi = 0; qi < 2; ++qi) {
                #pragma unroll
                for (int j = 0; j < 4; ++j) {
                    pb[qi][j]     = (__bf16)exp2f(s[qi][2 * ks][j]);
                    pb[qi][4 + j] = (__bf16)exp2f(s[qi][2 * ks + 1][j]);
                }
                accl[qi] = MFMA_BF16(vones, pb[qi], accl[qi]);
            }
            #pragma unroll
            for (int of = 0; of < 4; ++of) {
                const bf16x8 vf = *(const bf16x8*)(VB + ((ks * 4 + of) * 64 + lane) * 16);
                #pragma unroll
                for (int qi = 0; qi < 2; ++qi)
                    acc[qi][of] = MFMA_BF16(vf, pb[qi], acc[qi][of]);
            }
        }
    }
    #pragma unroll
    for (int qi = 0; qi < 2; ++qi) {
        const float inv = 1.f / accl[qi][0];
        const int qq = q0 + qi * 16 + lr;
        #pragma unroll
        for (int of = 0; of < 4; ++of) {
            bf16x4 o;
            #pragma unroll
            for (int r = 0; r < 4; ++r) o[r] = (__bf16)(acc[qi][of][r] * inv);
            *(bf16x4*)(out + ((size_t)b * LL + qq) * HIDC + h * HD + of * 16 + lg * 4) = o;
        }
    }
}

extern "C" void kernel_launch(void* const* d_in, const int* in_sizes, int n_in,
                              void* d_out, int out_size, void* d_ws, size_t ws_size,
                              hipStream_t stream) {
    const float* x_img = (const float*)d_in[0];
    const float* cond  = (const float*)d_in[1];
    const float* wq    = (const float*)d_in[2];
    const float* bq    = (const float*)d_in[3];
    const float* wk    = (const float*)d_in[4];
    const float* bk    = (const float*)d_in[5];
    const float* wv    = (const float*)d_in[6];
    const float* bv    = (const float*)d_in[7];
    const float* wo    = (const float*)d_in[8];
    const float* bo    = (const float*)d_in[9];
    const float* w_ada = (const float*)d_in[10];
    const float* b_ada = (const float*)d_in[11];
    const float* w1    = (const float*)d_in[12];
    const float* b1    = (const float*)d_in[13];
    const float* w2    = (const float*)d_in[14];
    const float* b2    = (const float*)d_in[15];
    const float* ln1s  = (const float*)d_in[16];
    const float* ln1b  = (const float*)d_in[17];
    const float* ln2s  = (const float*)d_in[18];
    const float* ln2b  = (const float*)d_in[19];

    char* ws = (char*)d_ws;
    __bf16* wqkvT = (__bf16*)(ws + OFF_WQKVT);
    __bf16* woT   = (__bf16*)(ws + OFF_WOT);
    __bf16* w1T   = (__bf16*)(ws + OFF_W1T);
    __bf16* w2T   = (__bf16*)(ws + OFF_W2T);
    float*  bqkv  = (float*)(ws + OFF_BQKV);
    float*  cbuf  = (float*)(ws + OFF_C);
    __bf16* hbuf  = (__bf16*)(ws + OFF_H);
    __bf16* aobuf = (__bf16*)(ws + OFF_AO);
    __bf16* qkv   = (__bf16*)(ws + OFF_QKV);
    __bf16* xbuf  = (__bf16*)(ws + OFF_QKV);   // bf16 x, aliases qkv (dead by then)

    dim3 blk(256);
    dim3 blk512(512);

    tcvt6_k<<<6 * 144, blk, 0, stream>>>(wq, wk, wv, wo, w1, w2, wqkvT);
    bcat_k<<<9, blk, 0, stream>>>(bq, bk, bv, bqkv);
    ada_k<<<144, blk, 0, stream>>>(cond, w_ada, b_ada, cbuf);

    // h = modulate(LN1(x_img))  (wave-per-row, float4)
    ln_mod_f4_k<<<MROWS / 4, blk, 0, stream>>>(x_img, ln1s, ln1b, cbuf, 0, 768, hbuf);

    // qkv = h @ [wq|wk|wv] + b  (q scaled, v lane-linear fragments)
    gemm256_k<0><<<2304, blk512, 0, stream>>>(hbuf, wqkvT, bqkv, 9, (void*)qkv);

    // attention -> attn_out  (4-wave blocks, 128 q-rows — measured best config)
    attn_k<<<BB * NHEAD * 8, blk, 0, stream>>>(qkv, qkv + QKV1, qkv + 2 * QKV1, aobuf);

    // x = x_img + gate_msa * (attn_out @ wo + bo)   -> bf16   (128x128 m97-shape GEMM)
    gemm128_k<3><<<3072, blk, 0, stream>>>(aobuf, woT, bo, 6, x_img, nullptr, cbuf + 2 * 768, (void*)xbuf);

    // h2 = modulate(LN2(x))  (wave-per-row, bf16 input)
    ln_mod_b_k<<<MROWS / 4, blk, 0, stream>>>(xbuf, ln2s, ln2b, cbuf, 3 * 768, 4 * 768, hbuf);

    // mlp hidden = silu(h2 @ w1 + b1)
    gemm128_k<2><<<3072, blk, 0, stream>>>(hbuf, w1T, b1, 6, nullptr, nullptr, nullptr, (void*)aobuf);

    // out = x + gate_mlp * (mlp_hidden @ w2 + b2)   (f32 final output)
    gemm128_k<4><<<3072, blk, 0, stream>>>(aobuf, w2T, b2, 6, nullptr, xbuf, cbuf + 5 * 768, d_out);

    (void)in_sizes; (void)n_in; (void)out_size; (void)ws_size;
}

// Round 19
// 1081.750 us; speedup vs baseline: 1.0430x; 1.0430x over previous
//
#include <hip/hip_runtime.h>
#include <hip/hip_bf16.h>

typedef __bf16 bf16x8 __attribute__((ext_vector_type(8)));
typedef __bf16 bf16x4 __attribute__((ext_vector_type(4)));
typedef float  f32x4  __attribute__((ext_vector_type(4)));

#define MFMA_BF16(A_, B_, C_) __builtin_amdgcn_mfma_f32_16x16x32_bf16(A_, B_, C_, 0, 0, 0)

static constexpr int    HIDC  = 768;
static constexpr int    BB    = 64;
static constexpr int    LL    = 1024;
static constexpr int    MROWS = BB * LL;          // 65536
static constexpr int    NHEAD = 12;
static constexpr int    HD    = 64;
static constexpr size_t QKV1  = (size_t)BB * NHEAD * LL * HD;   // 50331648 elems
static constexpr float  QSCALE = 0.1803368801111204f;           // 0.125 * log2(e)

// ---- workspace layout (bytes) ----
static constexpr size_t OFF_WQKVT = 0;                                    // bf16 [2304][768] (+wo,w1,w2 after)
static constexpr size_t OFF_WOT   = OFF_WQKVT + (size_t)2304 * 768 * 2;
static constexpr size_t OFF_W1T   = OFF_WOT   + (size_t)768 * 768 * 2;
static constexpr size_t OFF_W2T   = OFF_W1T   + (size_t)768 * 768 * 2;
static constexpr size_t OFF_BQKV  = OFF_W2T   + (size_t)768 * 768 * 2;    // f32 [2304]
static constexpr size_t OFF_C     = OFF_BQKV  + (size_t)2304 * 4;         // f32 [64][4608]
static constexpr size_t OFF_H     = OFF_C     + (size_t)64 * 4608 * 4;    // bf16 h / h2
static constexpr size_t OFF_AO    = OFF_H     + (size_t)MROWS * HIDC * 2; // bf16 attn_out / mlp_h
static constexpr size_t OFF_QKV   = OFF_AO    + (size_t)MROWS * HIDC * 2; // bf16 q,k,[v frag]; later bf16 x

__device__ __forceinline__ void async16(const __bf16* g, __bf16* l) {
    __builtin_amdgcn_global_load_lds((const __attribute__((address_space(1))) void*)g,
                                     (__attribute__((address_space(3))) void*)l, 16, 0, 0);
}

#define PH_BARRIER() do { __builtin_amdgcn_sched_barrier(0); asm volatile("" ::: "memory"); \
    __builtin_amdgcn_s_barrier(); asm volatile("" ::: "memory"); __builtin_amdgcn_sched_barrier(0); } while (0)

// ---------------- weight transpose + cast (LDS-tiled, coalesced): dst[n][k] = bf16(src[k][n]) ----------------
__global__ __launch_bounds__(256) void tcvt6_k(const float* __restrict__ s0, const float* __restrict__ s1,
                                               const float* __restrict__ s2, const float* __restrict__ s3,
                                               const float* __restrict__ s4, const float* __restrict__ s5,
                                               __bf16* __restrict__ dbase) {
    __shared__ float t[64][65];
    const int bid = blockIdx.x;           // 6 * 144
    const int widx = bid / 144;
    const int tb = bid - widx * 144;      // 12x12 tiles of 64
    const int kt = tb / 12, nt = tb - kt * 12;
    const float* src = (widx == 0) ? s0 : (widx == 1) ? s1 : (widx == 2) ? s2
                     : (widx == 3) ? s3 : (widx == 4) ? s4 : s5;
    const int tid = threadIdx.x;
    const int r = tid >> 4, c4 = (tid & 15) * 4;
    #pragma unroll
    for (int i = 0; i < 4; ++i) {
        const float4 v = *(const float4*)(src + (size_t)(kt * 64 + r + 16 * i) * 768 + nt * 64 + c4);
        t[r + 16 * i][c4 + 0] = v.x; t[r + 16 * i][c4 + 1] = v.y;
        t[r + 16 * i][c4 + 2] = v.z; t[r + 16 * i][c4 + 3] = v.w;
    }
    __syncthreads();
    const int n = tid >> 2, kg = (tid & 3) * 8;
    #pragma unroll
    for (int i = 0; i < 2; ++i) {
        const int k = kg + i * 32;
        bf16x8 o;
        #pragma unroll
        for (int j = 0; j < 8; ++j) o[j] = (__bf16)t[k + j][n];
        *(bf16x8*)(dbase + (size_t)widx * 768 * 768 + (size_t)(nt * 64 + n) * 768 + kt * 64 + k) = o;
    }
}

__global__ __launch_bounds__(256) void bcat_k(const float* __restrict__ bq, const float* __restrict__ bk,
                                              const float* __restrict__ bv, float* __restrict__ bqkv) {
    int i = blockIdx.x * 256 + threadIdx.x;
    if (i < 2304) {
        int w = i / 768, r = i - w * 768;
        const float* p = (w == 0) ? bq : (w == 1) ? bk : bv;
        bqkv[i] = p[r];
    }
}

// ---------------- adaLN: c[64][4608] = silu(cond) @ w_ada + b_ada ----------------
__global__ __launch_bounds__(256) void ada_k(const float* __restrict__ cond, const float* __restrict__ w_ada,
                                             const float* __restrict__ b_ada, float* __restrict__ c) {
    __shared__ float s[8][768];
    const int tid = threadIdx.x;
    const int bt = blockIdx.x / 18;
    const int nt = blockIdx.x % 18;
    #pragma unroll
    for (int i = 0; i < 24; ++i) {
        int idx = i * 256 + tid;
        int bb = idx / 768, kk = idx - bb * 768;
        float v = cond[(size_t)(bt * 8 + bb) * 768 + kk];
        s[bb][kk] = v / (1.f + __expf(-v));
    }
    __syncthreads();
    const int n = nt * 256 + tid;
    float acc[8];
    #pragma unroll
    for (int j = 0; j < 8; ++j) acc[j] = 0.f;
    for (int k = 0; k < 768; ++k) {
        float w = w_ada[(size_t)k * 4608 + n];
        #pragma unroll
        for (int j = 0; j < 8; ++j) acc[j] += s[j][k] * w;
    }
    float bias = b_ada[n];
    #pragma unroll
    for (int j = 0; j < 8; ++j) c[(size_t)(bt * 8 + j) * 4608 + n] = acc[j] + bias;
}

// ---------------- LayerNorm + modulate, wave-per-row (f32 input) -> bf16 ----------------
__global__ __launch_bounds__(256) void ln_mod_f4_k(const float* __restrict__ x,
                                                   const float* __restrict__ lns, const float* __restrict__ lnb,
                                                   const float* __restrict__ c, int shift_off, int scale_off,
                                                   __bf16* __restrict__ out) {
    const int wave = threadIdx.x >> 6, lane = threadIdx.x & 63;
    const int row = blockIdx.x * 4 + wave;
    const size_t base = (size_t)row * HIDC;
    const int b = row >> 10;
    float4 v[3];
    #pragma unroll
    for (int i = 0; i < 3; ++i) v[i] = *(const float4*)(x + base + (i * 64 + lane) * 4);
    float s = 0.f, ss = 0.f;
    #pragma unroll
    for (int i = 0; i < 3; ++i) {
        s  += v[i].x + v[i].y + v[i].z + v[i].w;
        ss += v[i].x * v[i].x + v[i].y * v[i].y + v[i].z * v[i].z + v[i].w * v[i].w;
    }
    #pragma unroll
    for (int off = 1; off < 64; off <<= 1) { s += __shfl_xor(s, off); ss += __shfl_xor(ss, off); }
    const float mu   = s * (1.f / 768.f);
    const float var  = ss * (1.f / 768.f) - mu * mu;
    const float rstd = rsqrtf(var + 1e-6f);
    const float* cb = c + (size_t)b * 4608;
    #pragma unroll
    for (int i = 0; i < 3; ++i) {
        bf16x4 o;
        const float vv[4] = {v[i].x, v[i].y, v[i].z, v[i].w};
        #pragma unroll
        for (int j = 0; j < 4; ++j) {
            const int col = (i * 64 + lane) * 4 + j;
            float val = (vv[j] - mu) * rstd * lns[col] + lnb[col];
            val = val * (1.f + cb[scale_off + col]) + cb[shift_off + col];
            o[j] = (__bf16)val;
        }
        *(bf16x4*)(out + base + (i * 64 + lane) * 4) = o;
    }
}

// ---------------- LayerNorm + modulate, wave-per-row (bf16 input) -> bf16 ----------------
__global__ __launch_bounds__(256) void ln_mod_b_k(const __bf16* __restrict__ x,
                                                  const float* __restrict__ lns, const float* __restrict__ lnb,
                                                  const float* __restrict__ c, int shift_off, int scale_off,
                                                  __bf16* __restrict__ out) {
    const int wave = threadIdx.x >> 6, lane = threadIdx.x & 63;
    const int row = blockIdx.x * 4 + wave;
    const size_t base = (size_t)row * HIDC;
    const int b = row >> 10;
    float v[12];
    #pragma unroll
    for (int i = 0; i < 3; ++i) {
        const bf16x4 xv = *(const bf16x4*)(x + base + (i * 64 + lane) * 4);
        #pragma unroll
        for (int j = 0; j < 4; ++j) v[i * 4 + j] = (float)xv[j];
    }
    float s = 0.f, ss = 0.f;
    #pragma unroll
    for (int i = 0; i < 12; ++i) { s += v[i]; ss += v[i] * v[i]; }
    #pragma unroll
    for (int off = 1; off < 64; off <<= 1) { s += __shfl_xor(s, off); ss += __shfl_xor(ss, off); }
    const float mu   = s * (1.f / 768.f);
    const float var  = ss * (1.f / 768.f) - mu * mu;
    const float rstd = rsqrtf(var + 1e-6f);
    const float* cb = c + (size_t)b * 4608;
    #pragma unroll
    for (int i = 0; i < 3; ++i) {
        bf16x4 o;
        #pragma unroll
        for (int j = 0; j < 4; ++j) {
            const int col = (i * 64 + lane) * 4 + j;
            float val = (v[i * 4 + j] - mu) * rstd * lns[col] + lnb[col];
            val = val * (1.f + cb[scale_off + col]) + cb[shift_off + col];
            o[j] = (__bf16)val;
        }
        *(bf16x4*)(out + base + (i * 64 + lane) * 4) = o;
    }
}

// ================ 256x256 GEMM: 2 barriers/K-tile (round-16, all four GEMMs) ================
// EPI: 0 = QKV scatter (V packed bf16x4); 2 = silu->bf16; 3 = x_img(f32)+gate*val->bf16; 4 = x(bf16)+gate*val->f32
template<int EPI>
__global__ __launch_bounds__(512, 2) void gemm256_k(const __bf16* __restrict__ A, const __bf16* __restrict__ BT,
                                                    const float* __restrict__ bias, int NBLK,
                                                    const float* __restrict__ e_res, const __bf16* __restrict__ e_resb,
                                                    const float* __restrict__ e_gate, void* __restrict__ out0) {
    constexpr int K = 768;
    constexpr int NKT = K / 64;           // 12 K-tiles
    __shared__ __attribute__((aligned(16))) unsigned char LDSB[131072];
    const int tid = threadIdx.x;
    const int nwg = gridDim.x;
    const int cpx = nwg >> 3;
    const int bid = blockIdx.x;
    const int swz = (bid & 7) * cpx + (bid >> 3);   // XCD-aware, bijective (nwg%8==0)
    const int mb = swz / NBLK, nb = swz - mb * NBLK;
    const size_t m0 = (size_t)mb * 256;
    const int n0 = nb * 256;
    const int wave = tid >> 6, lane = tid & 63;
    const int wm = wave >> 2, wn = wave & 3;
    const int lr = lane & 15, lg = lane >> 4;

    int prow[2], pcol[2], pphys[2];
    #pragma unroll
    for (int i = 0; i < 2; ++i) {
        int p = (i * 512 + tid) * 16;
        prow[i]  = p >> 7;
        pcol[i]  = ((p & 127) ^ ((prow[i] & 7) << 4)) >> 1;
        pphys[i] = p;
    }
    auto STAGE = [&](const __bf16* gbase, size_t rowstart, int kt, int regoff) {
        #pragma unroll
        for (int i = 0; i < 2; ++i) {
            const __bf16* g = gbase + (rowstart + (size_t)prow[i]) * K + kt * 64 + pcol[i];
            async16(g, (__bf16*)(LDSB + regoff + pphys[i]));
        }
    };
    auto AFRAG = [&](int db, int mf, int ks) -> bf16x8 {
        const int row = mf * 16 + lr;
        const int ph = row * 128 + ((ks * 64 + lg * 16) ^ ((row & 7) << 4));
        return *(const bf16x8*)(LDSB + db * 65536 + wm * 16384 + ph);
    };
    auto BFRAG = [&](int db, int nf, int ks) -> bf16x8 {
        const int row = (wn & 1) * 64 + nf * 16 + lr;
        const int ph = row * 128 + ((ks * 64 + lg * 16) ^ ((row & 7) << 4));
        return *(const bf16x8*)(LDSB + db * 65536 + 32768 + (wn >> 1) * 16384 + ph);
    };

    f32x4 acc[8][4];
    #pragma unroll
    for (int i = 0; i < 8; ++i)
        #pragma unroll
        for (int j = 0; j < 4; ++j) acc[i][j] = (f32x4){0.f, 0.f, 0.f, 0.f};
    bf16x8 Af[4][2], Af2[4][2], Bf[4][2];

    STAGE(BT, (size_t)n0,       0, 32768);
    STAGE(BT, (size_t)n0 + 128, 0, 49152);
    STAGE(A,  m0,               0, 0);
    STAGE(A,  m0 + 128,         0, 16384);
    STAGE(BT, (size_t)n0,       1, 65536 + 32768);
    STAGE(BT, (size_t)n0 + 128, 1, 65536 + 49152);
    asm volatile("s_waitcnt vmcnt(4)" ::: "memory");
    PH_BARRIER();

    #pragma unroll 2
    for (int g = 0; g < NKT; ++g) {
        const int db = g & 1, dbn = db ^ 1;
        #pragma unroll
        for (int mf = 0; mf < 4; ++mf) { Af[mf][0] = AFRAG(db, mf, 0); Af[mf][1] = AFRAG(db, mf, 1); }
        #pragma unroll
        for (int nf = 0; nf < 4; ++nf) { Bf[nf][0] = BFRAG(db, nf, 0); Bf[nf][1] = BFRAG(db, nf, 1); }
        if (g + 1 < NKT) {
            STAGE(A, m0,       g + 1, dbn * 65536);
            STAGE(A, m0 + 128, g + 1, dbn * 65536 + 16384);
        }
        __builtin_amdgcn_s_setprio(1);
        #pragma unroll
        for (int ks = 0; ks < 2; ++ks)
            #pragma unroll
            for (int mf = 0; mf < 4; ++mf)
                #pragma unroll
                for (int nf = 0; nf < 4; ++nf)
                    acc[mf][nf] = MFMA_BF16(Af[mf][ks], Bf[nf][ks], acc[mf][nf]);
        __builtin_amdgcn_s_setprio(0);
        PH_BARRIER();
        #pragma unroll
        for (int mf = 0; mf < 4; ++mf) { Af2[mf][0] = AFRAG(db, mf + 4, 0); Af2[mf][1] = AFRAG(db, mf + 4, 1); }
        if (g + 2 < NKT) {
            STAGE(BT, (size_t)n0,       g + 2, db * 65536 + 32768);
            STAGE(BT, (size_t)n0 + 128, g + 2, db * 65536 + 49152);
        }
        __builtin_amdgcn_s_setprio(1);
        #pragma unroll
        for (int ks = 0; ks < 2; ++ks)
            #pragma unroll
            for (int mf = 0; mf < 4; ++mf)
                #pragma unroll
                for (int nf = 0; nf < 4; ++nf)
                    acc[mf + 4][nf] = MFMA_BF16(Af2[mf][ks], Bf[nf][ks], acc[mf + 4][nf]);
        __builtin_amdgcn_s_setprio(0);
        if (g < NKT - 2)       asm volatile("s_waitcnt vmcnt(4)" ::: "memory");
        else if (g == NKT - 2) asm volatile("s_waitcnt vmcnt(0)" ::: "memory");
        if (g + 1 < NKT) PH_BARRIER();
    }

    #pragma unroll
    for (int mf = 0; mf < 8; ++mf) {
        #pragma unroll
        for (int nf = 0; nf < 4; ++nf) {
            const int col = wn * 64 + nf * 16 + lr;
            const int n = n0 + col;
            const int row0 = wm * 128 + mf * 16 + lg * 4;
            const size_t mbase = m0 + row0;
            float v4[4];
            #pragma unroll
            for (int r = 0; r < 4; ++r) v4[r] = acc[mf][nf][r] + bias[n];
            if constexpr (EPI == 0) {
                const int which = n / 768, rem = n - which * 768;
                const int hh = rem >> 6, dd = rem & 63;
                const size_t bI = mbase >> 10;
                const size_t lI0 = mbase & 1023;
                if (which == 0) {
                    #pragma unroll
                    for (int r = 0; r < 4; ++r)
                        ((__bf16*)out0)[(((size_t)bI * NHEAD + hh) * LL + lI0 + r) * HD + dd] = (__bf16)(v4[r] * QSCALE);
                } else if (which == 1) {
                    #pragma unroll
                    for (int r = 0; r < 4; ++r)
                        ((__bf16*)out0)[QKV1 + (((size_t)bI * NHEAD + hh) * LL + lI0 + r) * HD + dd] = (__bf16)v4[r];
                } else {
                    const int tile = (int)(lI0 >> 6), kv = (int)(lI0 & 63);
                    const int ks = kv >> 5, r5 = kv & 31;
                    const int lgj = (r5 >> 2) & 3;
                    const int jb = (r5 >> 4) << 2;
                    const int of = dd >> 4, lr2 = dd & 15;
                    bf16x4 pk;
                    #pragma unroll
                    for (int r = 0; r < 4; ++r) pk[r] = (__bf16)v4[r];
                    *(bf16x4*)((__bf16*)out0 + 2 * QKV1 + ((size_t)bI * NHEAD + hh) * (LL * HD)
                               + (size_t)tile * 4096 + ((ks * 4 + of) * 64 + lgj * 16 + lr2) * 8 + jb) = pk;
                }
            } else {
                #pragma unroll
                for (int r = 0; r < 4; ++r) {
                    const size_t m = mbase + r;
                    if constexpr (EPI == 2) {
                        float sv = v4[r] / (1.f + __expf(-v4[r]));
                        ((__bf16*)out0)[m * HIDC + n] = (__bf16)sv;
                    } else if constexpr (EPI == 3) {
                        size_t bI = m >> 10;
                        float gg = e_gate[bI * 4608 + n];
                        ((__bf16*)out0)[m * HIDC + n] = (__bf16)(e_res[m * HIDC + n] + gg * v4[r]);
                    } else {
                        size_t bI = m >> 10;
                        float gg = e_gate[bI * 4608 + n];
                        ((float*)out0)[m * HIDC + n] = (float)e_resb[m * HIDC + n] + gg * v4[r];
                    }
                }
            }
        }
    }
}

// ================ flash attention: 4-wave blocks (measured best, 288 us), ring-2, unshifted exp2 ================
__global__ __launch_bounds__(256, 4) void attn_k(const __bf16* __restrict__ qb, const __bf16* __restrict__ kb,
                                                 const __bf16* __restrict__ v2g, __bf16* __restrict__ out) {
    __shared__ __attribute__((aligned(16))) unsigned char LDSA[32768];
    const int nwg = gridDim.x;       // 6144
    const int cpx = nwg >> 3;
    const int bid = blockIdx.x;
    const int swz = (bid & 7) * cpx + (bid >> 3);
    const int bh = swz >> 3;
    const int qt = swz & 7;
    const int b = bh / NHEAD, h = bh - b * NHEAD;
    const int tid = threadIdx.x;
    const int wave = tid >> 6, lane = tid & 63;
    const int lr = lane & 15, lg = lane >> 4;
    const size_t base = (size_t)bh * LL * HD;    // q,k: [bh][l][d]; v2: [bh][tile][4096]

    const int q0 = qt * 128 + wave * 32;
    bf16x8 qf[2][2];
    #pragma unroll
    for (int qi = 0; qi < 2; ++qi) {
        const __bf16* qrow = qb + base + (size_t)(q0 + qi * 16 + lr) * HD;
        qf[qi][0] = *(const bf16x8*)(qrow + lg * 8);
        qf[qi][1] = *(const bf16x8*)(qrow + 32 + lg * 8);
    }
    __builtin_amdgcn_sched_barrier(0);

    int krow[2], kcol[2];
    #pragma unroll
    for (int i = 0; i < 2; ++i) {
        int pp = (i * 256 + tid) * 16;
        krow[i] = pp >> 7;
        kcol[i] = (pp & 127) ^ ((krow[i] & 7) << 4);
    }
    auto STAGE = [&](int t) {
        unsigned char* Lb = LDSA + (t & 1) * 16384;
        const int kv0 = t * 64;
        #pragma unroll
        for (int i = 0; i < 2; ++i) {
            const __bf16* g = kb + base + (size_t)(kv0 + krow[i]) * HD + (kcol[i] >> 1);
            async16(g, (__bf16*)(Lb + (i * 256 + tid) * 16));
        }
        #pragma unroll
        for (int i = 0; i < 2; ++i) {
            int pp = (i * 256 + tid) * 16;
            const __bf16* g = v2g + base + (size_t)t * 4096 + (pp >> 1);
            async16(g, (__bf16*)(Lb + 8192 + pp));
        }
    };

    bf16x8 vones;
    #pragma unroll
    for (int j = 0; j < 8; ++j) vones[j] = (__bf16)1.0f;

    f32x4 acc[2][4];
    f32x4 accl[2];    // ones-MFMA row-sum accumulator (reg 0 used)
    #pragma unroll
    for (int qi = 0; qi < 2; ++qi) {
        accl[qi] = (f32x4){0.f, 0.f, 0.f, 0.f};
        #pragma unroll
        for (int i = 0; i < 4; ++i) acc[qi][i] = (f32x4){0.f, 0.f, 0.f, 0.f};
    }

    STAGE(0);

    for (int t = 0; t < LL / 64; ++t) {
        asm volatile("s_waitcnt vmcnt(0)" ::: "memory");
        PH_BARRIER();
        if (t + 1 < LL / 64) STAGE(t + 1);
        const unsigned char* KB = LDSA + (t & 1) * 16384;
        const unsigned char* VB = KB + 8192;

        f32x4 s[2][4];
        #pragma unroll
        for (int sf = 0; sf < 4; ++sf) {
            const int row = sf * 16 + lr;
            const bf16x8 kf0 = *(const bf16x8*)(KB + row * 128 + ((lg * 16) ^ ((row & 7) << 4)));
            const bf16x8 kf1 = *(const bf16x8*)(KB + row * 128 + ((64 + lg * 16) ^ ((row & 7) << 4)));
            #pragma unroll
            for (int qi = 0; qi < 2; ++qi) {
                f32x4 tt = (f32x4){0.f, 0.f, 0.f, 0.f};
                tt = MFMA_BF16(kf0, qf[qi][0], tt);
                tt = MFMA_BF16(kf1, qf[qi][1], tt);
                s[qi][sf] = tt;
            }
        }
        // P = exp2(S) — unshifted; exact normalization by ones-MFMA row-sum at the end
        #pragma unroll
        for (int ks = 0; ks < 2; ++ks) {
            bf16x8 pb[2];
            #pragma unroll
            for (int qi = 0; qi < 2; ++qi) {
                #pragma unroll
                for (int j = 0; j < 4; ++j) {
                    pb[qi][j]     = (__bf16)exp2f(s[qi][2 * ks][j]);
                    pb[qi][4 + j] = (__bf16)exp2f(s[qi][2 * ks + 1][j]);
                }
                accl[qi] = MFMA_BF16(vones, pb[qi], accl[qi]);
            }
            #pragma unroll
            for (int of = 0; of < 4; ++of) {
                const bf16x8 vf = *(const bf16x8*)(VB + ((ks * 4 + of) * 64 + lane) * 16);
                #pragma unroll
                for (int qi = 0; qi < 2; ++qi)
                    acc[qi][of] = MFMA_BF16(vf, pb[qi], acc[qi][of]);
            }
        }
    }
    #pragma unroll
    for (int qi = 0; qi < 2; ++qi) {
        const float inv = 1.f / accl[qi][0];
        const int qq = q0 + qi * 16 + lr;
        #pragma unroll
        for (int of = 0; of < 4; ++of) {
            bf16x4 o;
            #pragma unroll
            for (int r = 0; r < 4; ++r) o[r] = (__bf16)(acc[qi][of][r] * inv);
            *(bf16x4*)(out + ((size_t)b * LL + qq) * HIDC + h * HD + of * 16 + lg * 4) = o;
        }
    }
}

extern "C" void kernel_launch(void* const* d_in, const int* in_sizes, int n_in,
                              void* d_out, int out_size, void* d_ws, size_t ws_size,
                              hipStream_t stream) {
    const float* x_img = (const float*)d_in[0];
    const float* cond  = (const float*)d_in[1];
    const float* wq    = (const float*)d_in[2];
    const float* bq    = (const float*)d_in[3];
    const float* wk    = (const float*)d_in[4];
    const float* bk    = (const float*)d_in[5];
    const float* wv    = (const float*)d_in[6];
    const float* bv    = (const float*)d_in[7];
    const float* wo    = (const float*)d_in[8];
    const float* bo    = (const float*)d_in[9];
    const float* w_ada = (const float*)d_in[10];
    const float* b_ada = (const float*)d_in[11];
    const float* w1    = (const float*)d_in[12];
    const float* b1    = (const float*)d_in[13];
    const float* w2    = (const float*)d_in[14];
    const float* b2    = (const float*)d_in[15];
    const float* ln1s  = (const float*)d_in[16];
    const float* ln1b  = (const float*)d_in[17];
    const float* ln2s  = (const float*)d_in[18];
    const float* ln2b  = (const float*)d_in[19];

    char* ws = (char*)d_ws;
    __bf16* wqkvT = (__bf16*)(ws + OFF_WQKVT);
    __bf16* woT   = (__bf16*)(ws + OFF_WOT);
    __bf16* w1T   = (__bf16*)(ws + OFF_W1T);
    __bf16* w2T   = (__bf16*)(ws + OFF_W2T);
    float*  bqkv  = (float*)(ws + OFF_BQKV);
    float*  cbuf  = (float*)(ws + OFF_C);
    __bf16* hbuf  = (__bf16*)(ws + OFF_H);
    __bf16* aobuf = (__bf16*)(ws + OFF_AO);
    __bf16* qkv   = (__bf16*)(ws + OFF_QKV);
    __bf16* xbuf  = (__bf16*)(ws + OFF_QKV);   // bf16 x, aliases qkv (dead by then)

    dim3 blk(256);
    dim3 blk512(512);

    tcvt6_k<<<6 * 144, blk, 0, stream>>>(wq, wk, wv, wo, w1, w2, wqkvT);
    bcat_k<<<9, blk, 0, stream>>>(bq, bk, bv, bqkv);
    ada_k<<<144, blk, 0, stream>>>(cond, w_ada, b_ada, cbuf);

    // h = modulate(LN1(x_img))  (wave-per-row, float4)
    ln_mod_f4_k<<<MROWS / 4, blk, 0, stream>>>(x_img, ln1s, ln1b, cbuf, 0, 768, hbuf);

    // qkv = h @ [wq|wk|wv] + b  (q scaled, v lane-linear fragments)
    gemm256_k<0><<<2304, blk512, 0, stream>>>(hbuf, wqkvT, bqkv, 9, nullptr, nullptr, nullptr, (void*)qkv);

    // attention -> attn_out  (4-wave blocks, 128 q-rows — measured best)
    attn_k<<<BB * NHEAD * 8, blk, 0, stream>>>(qkv, qkv + QKV1, qkv + 2 * QKV1, aobuf);

    // x = x_img + gate_msa * (attn_out @ wo + bo)   -> bf16
    gemm256_k<3><<<768, blk512, 0, stream>>>(aobuf, woT, bo, 3, x_img, nullptr, cbuf + 2 * 768, (void*)xbuf);

    // h2 = modulate(LN2(x))  (wave-per-row, bf16 input)
    ln_mod_b_k<<<MROWS / 4, blk, 0, stream>>>(xbuf, ln2s, ln2b, cbuf, 3 * 768, 4 * 768, hbuf);

    // mlp hidden = silu(h2 @ w1 + b1)
    gemm256_k<2><<<768, blk512, 0, stream>>>(hbuf, w1T, b1, 3, nullptr, nullptr, nullptr, (void*)aobuf);

    // out = x + gate_mlp * (mlp_hidden @ w2 + b2)   (f32 final output)
    gemm256_k<4><<<768, blk512, 0, stream>>>(aobuf, w2T, b2, 3, nullptr, xbuf, cbuf + 5 * 768, d_out);

    (void)in_sizes; (void)n_in; (void)out_size; (void)ws_size;
}